// Round 2
// baseline (512.526 us; speedup 1.0000x reference)
//
#include <hip/hip_runtime.h>

// Problem constants
#define Bn 256
#define Vn 512
#define Fn 256
// O = 2 hard-coded throughout.

// Single fully-fused kernel: one block of 1024 threads per batch element
// (grid 256 = one block per CU, 16 waves/CU).
//
// Phase 1 (streaming, HBM-bound): wave w handles rows v = it*16 + w
// (32 rows each).  Per row: graphs row (512 int32) as 2x int4/lane,
// features row (256 f32) as float4/lane.  Bit-pack via ballot in a
// PERMUTED order: word j = q*4+c (q in {0,1}, c in {0..3}), bit L of
// word j <-> element 256q + 4L + c.  Degree (popcount) is order-
// invariant; phase 2 unpacks in the same order.  X@W (O=2) wave-reduced.
// All results go to LDS: P (32 KB), Y*dinv (4 KB), dinv (2 KB).
//
// Phase 2 (VALU, ~5 µs): thread t owns row r = t>>1, half h = t&1
// (elements 256h..256h+255).  256 fma-pairs per thread against the
// wave-uniform-broadcast ylds stream; halves combined via shfl_xor(.,1);
// bias+relu+head dot+block reduce+sigmoid.
__global__ __launch_bounds__(1024) void fused_gcn_kernel(
    const int* __restrict__ G,
    const float* __restrict__ X,
    const float* __restrict__ W,
    const float* __restrict__ lw,
    const float* __restrict__ lb,
    const float* __restrict__ cb,
    float* __restrict__ out) {
  __shared__ unsigned long long Plds[Vn][8];  // 32 KB packed adjacency
  __shared__ float2 ylds[Vn];                 // Y[v,:] * dinv[v]
  __shared__ float  dlds[Vn];                 // dinv[v]
  __shared__ float  wsum[16];

  int b    = blockIdx.x;
  int t    = threadIdx.x;
  int wave = t >> 6;   // 0..15
  int lane = t & 63;

  // Hoisted conv weights (W is [F,2] row-major, 2 KB, L1-resident).
  const float4* wr = (const float4*)W;
  float4 w0 = wr[lane * 2];      // {W[4L][0],W[4L][1],W[4L+1][0],W[4L+1][1]}
  float4 w1 = wr[lane * 2 + 1];  // {W[4L+2][0],W[4L+2][1],W[4L+3][0],W[4L+3][1]}

  // ---- Phase 1 ----
  for (int it = 0; it < 32; ++it) {
    int v = (it << 4) | wave;                 // wave-uniform row in batch
    size_t row = (size_t)b * Vn + v;

    const int4* g4 = (const int4*)(G + row * Vn);
    int4 A0 = g4[lane];                       // elements 4L .. 4L+3
    int4 A1 = g4[64 + lane];                  // elements 256+4L .. 256+4L+3
    const float4* xr = (const float4*)(X + row * Fn);
    float4 x = xr[lane];

    unsigned long long m0 = __ballot(A0.x != 0);
    unsigned long long m1 = __ballot(A0.y != 0);
    unsigned long long m2 = __ballot(A0.z != 0);
    unsigned long long m3 = __ballot(A0.w != 0);
    unsigned long long m4 = __ballot(A1.x != 0);
    unsigned long long m5 = __ballot(A1.y != 0);
    unsigned long long m6 = __ballot(A1.z != 0);
    unsigned long long m7 = __ballot(A1.w != 0);

    // Self-loop: element v -> word ((v>>8)<<2)|(v&3), bit (v>>2)&63.
    // All wave-uniform -> scalar branches.
    int widx = ((v >> 8) << 2) | (v & 3);
    unsigned long long db = 1ull << ((v >> 2) & 63);
    if      (widx == 0) m0 |= db;
    else if (widx == 1) m1 |= db;
    else if (widx == 2) m2 |= db;
    else if (widx == 3) m3 |= db;
    else if (widx == 4) m4 |= db;
    else if (widx == 5) m5 |= db;
    else if (widx == 6) m6 |= db;
    else                m7 |= db;

    int deg = __popcll(m0) + __popcll(m1) + __popcll(m2) + __popcll(m3) +
              __popcll(m4) + __popcll(m5) + __popcll(m6) + __popcll(m7);

    // X @ W (O=2)
    float s0 = x.x * w0.x + x.y * w0.z + x.z * w1.x + x.w * w1.z;
    float s1 = x.x * w0.y + x.y * w0.w + x.z * w1.y + x.w * w1.w;
    #pragma unroll
    for (int off = 32; off; off >>= 1) {
      s0 += __shfl_xor(s0, off);
      s1 += __shfl_xor(s1, off);
    }

    // Lane i (i<8) stores word i via unrolled cndmask chain.
    unsigned long long sel = m0;
    sel = (lane == 1) ? m1 : sel;
    sel = (lane == 2) ? m2 : sel;
    sel = (lane == 3) ? m3 : sel;
    sel = (lane == 4) ? m4 : sel;
    sel = (lane == 5) ? m5 : sel;
    sel = (lane == 6) ? m6 : sel;
    sel = (lane == 7) ? m7 : sel;
    if (lane < 8) Plds[v][lane] = sel;
    if (lane == 0) {
      float d = rsqrtf((float)deg);
      dlds[v] = d;
      ylds[v] = make_float2(s0 * d, s1 * d);  // fold column norm here
    }
  }
  __syncthreads();

  // ---- Phase 2 ----
  int r = t >> 1;                 // row this thread accumulates
  int h = t & 1;                  // element half: q = h
  float a0 = 0.f, a1 = 0.f;
  const float2* ybase = ylds + (h << 8);
  #pragma unroll
  for (int c = 0; c < 4; ++c) {
    unsigned long long m = Plds[r][(h << 2) | c];
    unsigned lo = (unsigned)m;
    unsigned hi = (unsigned)(m >> 32);
    const float2* base = ybase + c;           // element 256h + 4k + c
    #pragma unroll
    for (int k = 0; k < 32; ++k) {
      float s = (float)((lo >> k) & 1u);      // v_bfe + v_cvt
      float2 y = base[4 * k];                 // 2-address broadcast (free)
      a0 = fmaf(s, y.x, a0);
      a1 = fmaf(s, y.y, a1);
    }
    #pragma unroll
    for (int k = 0; k < 32; ++k) {
      float s = (float)((hi >> k) & 1u);
      float2 y = base[4 * k + 128];
      a0 = fmaf(s, y.x, a0);
      a1 = fmaf(s, y.y, a1);
    }
  }
  // Combine the two halves of row r (lanes 2r, 2r+1 are wave-adjacent).
  a0 += __shfl_xor(a0, 1);
  a1 += __shfl_xor(a1, 1);

  float c_acc = 0.f;
  if (h == 0) {
    float d = dlds[r];
    float cb0 = cb[0], cb1 = cb[1];
    const float2* lw2 = (const float2*)lw;    // lw flat index = r*2 + o
    float2 wv = lw2[r];
    float h0 = fmaxf(fmaf(d, a0, cb0), 0.f);
    float h1 = fmaxf(fmaf(d, a1, cb1), 0.f);
    c_acc = h0 * wv.x + h1 * wv.y;
  }
  #pragma unroll
  for (int off = 32; off; off >>= 1) c_acc += __shfl_xor(c_acc, off);
  if (lane == 0) wsum[wave] = c_acc;
  __syncthreads();
  if (t == 0) {
    float logit = lb[0];
    #pragma unroll
    for (int i = 0; i < 16; ++i) logit += wsum[i];
    out[b] = 1.0f / (1.0f + expf(-logit));
  }
}

extern "C" void kernel_launch(void* const* d_in, const int* in_sizes, int n_in,
                              void* d_out, int out_size, void* d_ws, size_t ws_size,
                              hipStream_t stream) {
  const float* features = (const float*)d_in[0];
  const int*   graphs   = (const int*)d_in[1];
  const float* conv_w   = (const float*)d_in[2];
  const float* conv_b   = (const float*)d_in[3];
  const float* lin_w    = (const float*)d_in[4];
  const float* lin_b    = (const float*)d_in[5];
  float* out = (float*)d_out;
  (void)d_ws; (void)ws_size;

  // One block per batch element; 1024 threads = 16 waves (one block/CU).
  fused_gcn_kernel<<<dim3(Bn), dim3(1024), 0, stream>>>(
      graphs, features, conv_w, lin_w, lin_b, conv_b, out);
}

// Round 3
// 438.425 us; speedup vs baseline: 1.1690x; 1.1690x over previous
//
#include <hip/hip_runtime.h>

// Problem constants
#define Bn 256
#define Vn 512
#define Fn 256
// O = 2 hard-coded throughout.

// Workspace layout (bytes):
//   packed adjacency bits: [Bn*Vn][8] uint64  at 0        (8 MB)
//   dinv:                  [Bn*Vn] float      at 8388608   (512 KB)
//   Ypre = (X@W)*dinv:     [Bn*Vn] float2     at 8912896   (1 MB)
#define WS_PACKED_OFF 0
#define WS_DINV_OFF   8388608
#define WS_Y_OFF      8912896

// Fused pack + degree + X@W kernel: one wave (64 lanes) per row (b*Vn + v).
//   Graphs row (512 int32 = 2 KB) loaded as 2x int4 per lane (16 B/lane).
//   Bit packing uses a PERMUTED order: word j = q*4+c (q in {0,1}, c in
//   {0..3}), bit L of word j <-> element 256q + 4L + c.  Degree (popcount)
//   is order-invariant; the aggregation kernel unpacks in the same order.
//   Y is written PRE-MULTIPLIED by dinv (column norm folded here).
__global__ __launch_bounds__(256) void fused_pack_xw_kernel(
    const int* __restrict__ G,
    const float* __restrict__ X,
    const float* __restrict__ W,
    unsigned long long* __restrict__ P,
    float* __restrict__ dinv,
    float2* __restrict__ Y) {
  int gid  = blockIdx.x * 256 + threadIdx.x;
  int row  = gid >> 6;          // b*Vn + v, wave-uniform
  int lane = gid & 63;
  int v    = row & (Vn - 1);

  // ---- issue all global loads up front (graphs + features + weights) ----
  const int4* g4 = (const int4*)(G + (size_t)row * Vn);
  int4 A0 = g4[lane];           // elements 4*lane   .. 4*lane+3
  int4 A1 = g4[64 + lane];      // elements 256+4*lane .. 256+4*lane+3

  const float4* xr = (const float4*)(X + (size_t)row * Fn);
  float4 x = xr[lane];
  const float4* wr = (const float4*)W;   // W is [F,2] row-major
  float4 w0 = wr[lane * 2];      // {W[4L][0],W[4L][1],W[4L+1][0],W[4L+1][1]}
  float4 w1 = wr[lane * 2 + 1];  // {W[4L+2][0],W[4L+2][1],W[4L+3][0],W[4L+3][1]}

  // ---- permuted ballots: word q*4+c, bit L <-> element 256q+4L+c ----
  unsigned long long m0 = __ballot(A0.x != 0);
  unsigned long long m1 = __ballot(A0.y != 0);
  unsigned long long m2 = __ballot(A0.z != 0);
  unsigned long long m3 = __ballot(A0.w != 0);
  unsigned long long m4 = __ballot(A1.x != 0);
  unsigned long long m5 = __ballot(A1.y != 0);
  unsigned long long m6 = __ballot(A1.z != 0);
  unsigned long long m7 = __ballot(A1.w != 0);

  // Self-loop bit: element v -> word ((v>>8)<<2)|(v&3), bit (v>>2)&63.
  // All wave-uniform -> scalar branches.
  int widx = ((v >> 8) << 2) | (v & 3);
  unsigned long long db = 1ull << ((v >> 2) & 63);
  if      (widx == 0) m0 |= db;
  else if (widx == 1) m1 |= db;
  else if (widx == 2) m2 |= db;
  else if (widx == 3) m3 |= db;
  else if (widx == 4) m4 |= db;
  else if (widx == 5) m5 |= db;
  else if (widx == 6) m6 |= db;
  else                m7 |= db;

  int deg = __popcll(m0) + __popcll(m1) + __popcll(m2) + __popcll(m3) +
            __popcll(m4) + __popcll(m5) + __popcll(m6) + __popcll(m7);

  // ---- X @ W (O=2) ----
  float s0 = x.x * w0.x + x.y * w0.z + x.z * w1.x + x.w * w1.z;
  float s1 = x.x * w0.y + x.y * w0.w + x.z * w1.y + x.w * w1.w;
  #pragma unroll
  for (int off = 32; off; off >>= 1) {
    s0 += __shfl_xor(s0, off);
    s1 += __shfl_xor(s1, off);
  }

  // Lane i (i<8) stores word i via unrolled cndmask chain.
  unsigned long long sel = m0;
  sel = (lane == 1) ? m1 : sel;
  sel = (lane == 2) ? m2 : sel;
  sel = (lane == 3) ? m3 : sel;
  sel = (lane == 4) ? m4 : sel;
  sel = (lane == 5) ? m5 : sel;
  sel = (lane == 6) ? m6 : sel;
  sel = (lane == 7) ? m7 : sel;
  if (lane < 8) P[(size_t)row * 8 + lane] = sel;
  if (lane == 0) {
    float d = rsqrtf((float)deg);
    dinv[row] = d;
    Y[row] = make_float2(s0 * d, s1 * d);   // column norm folded in
  }
}

// Aggregation + bias + relu + head dot + sigmoid.  One block of 512 threads
// per batch element.  Thread t owns row v = t.  LDS holds Ypre[b,w,:]
// (already * dinv[w]); bit k of word j = q*4+c maps to element 256q+4k+c,
// so elements 4k..4k+3 are CONSECUTIVE -> two uniform ds_read_b128 serve
// 4 bits.  8 independent accumulator chains (4 per channel) for ILP.
__global__ __launch_bounds__(512) void agg_head_kernel(
    const unsigned long long* __restrict__ P,
    const float* __restrict__ dinv,
    const float2* __restrict__ Y,
    const float* __restrict__ lw,
    const float* __restrict__ lb,
    const float* __restrict__ cb,
    float* __restrict__ out) {
  __shared__ float2 ylds[Vn];
  __shared__ float wsum[8];

  int b = blockIdx.x;
  int t = threadIdx.x;          // = row v

  // Issue this row's 64 B of mask words FIRST (hide HBM latency under
  // staging + barrier).
  const ulonglong2* p2 = (const ulonglong2*)(P + ((size_t)b * Vn + t) * 8);
  ulonglong2 q0 = p2[0];        // words 0,1  (q=0, c=0,1)
  ulonglong2 q1 = p2[1];        // words 2,3  (q=0, c=2,3)
  ulonglong2 q2 = p2[2];        // words 4,5  (q=1, c=0,1)
  ulonglong2 q3 = p2[3];        // words 6,7  (q=1, c=2,3)

  float d = dinv[b * Vn + t];
  ylds[t] = Y[b * Vn + t];      // pure copy (dinv already folded)
  __syncthreads();

  const float4* y4 = (const float4*)ylds;   // y4[i] = elements {2i, 2i+1}

  // 8 independent accumulator chains: ac{c}{o}, c = word-c (0..3), o = chan.
  float a0x = 0.f, a0y = 0.f, a1x = 0.f, a1y = 0.f;
  float a2x = 0.f, a2y = 0.f, a3x = 0.f, a3y = 0.f;

  #pragma unroll
  for (int q = 0; q < 2; ++q) {
    unsigned long long w0 = q ? q2.x : q0.x;   // c=0
    unsigned long long w1 = q ? q2.y : q0.y;   // c=1
    unsigned long long w2 = q ? q3.x : q1.x;   // c=2
    unsigned long long w3 = q ? q3.y : q1.y;   // c=3
    #pragma unroll
    for (int half = 0; half < 2; ++half) {
      unsigned b0 = half ? (unsigned)(w0 >> 32) : (unsigned)w0;
      unsigned b1 = half ? (unsigned)(w1 >> 32) : (unsigned)w1;
      unsigned b2 = half ? (unsigned)(w2 >> 32) : (unsigned)w2;
      unsigned b3 = half ? (unsigned)(w3 >> 32) : (unsigned)w3;
      int ibase = 128 * q + 64 * half;         // float4 index of element 4k
      #pragma unroll
      for (int k = 0; k < 32; ++k) {
        float4 ya = y4[ibase + 2 * k];         // elems 4K, 4K+1 (uniform)
        float4 yb = y4[ibase + 2 * k + 1];     // elems 4K+2, 4K+3
        float s0 = (float)((b0 >> k) & 1u);
        float s1 = (float)((b1 >> k) & 1u);
        float s2 = (float)((b2 >> k) & 1u);
        float s3 = (float)((b3 >> k) & 1u);
        a0x = fmaf(s0, ya.x, a0x); a0y = fmaf(s0, ya.y, a0y);
        a1x = fmaf(s1, ya.z, a1x); a1y = fmaf(s1, ya.w, a1y);
        a2x = fmaf(s2, yb.x, a2x); a2y = fmaf(s2, yb.y, a2y);
        a3x = fmaf(s3, yb.z, a3x); a3y = fmaf(s3, yb.w, a3y);
      }
    }
  }
  float A0 = (a0x + a1x) + (a2x + a3x);
  float A1 = (a0y + a1y) + (a2y + a3y);

  float cb0 = cb[0], cb1 = cb[1];
  const float2* lw2 = (const float2*)lw;      // lw flat index = v*2 + o
  float2 wv = lw2[t];

  float h0 = fmaxf(fmaf(d, A0, cb0), 0.f);
  float h1 = fmaxf(fmaf(d, A1, cb1), 0.f);
  float c = h0 * wv.x + h1 * wv.y;

  #pragma unroll
  for (int off = 32; off; off >>= 1) c += __shfl_xor(c, off);
  if ((t & 63) == 0) wsum[t >> 6] = c;
  __syncthreads();
  if (t == 0) {
    float logit = wsum[0] + wsum[1] + wsum[2] + wsum[3] +
                  wsum[4] + wsum[5] + wsum[6] + wsum[7] + lb[0];
    out[b] = 1.0f / (1.0f + expf(-logit));
  }
}

extern "C" void kernel_launch(void* const* d_in, const int* in_sizes, int n_in,
                              void* d_out, int out_size, void* d_ws, size_t ws_size,
                              hipStream_t stream) {
  const float* features = (const float*)d_in[0];
  const int*   graphs   = (const int*)d_in[1];
  const float* conv_w   = (const float*)d_in[2];
  const float* conv_b   = (const float*)d_in[3];
  const float* lin_w    = (const float*)d_in[4];
  const float* lin_b    = (const float*)d_in[5];
  float* out = (float*)d_out;

  char* ws = (char*)d_ws;
  unsigned long long* P = (unsigned long long*)(ws + WS_PACKED_OFF);
  float*  dinv = (float*)(ws + WS_DINV_OFF);
  float2* Y    = (float2*)(ws + WS_Y_OFF);

  // Fused pack+deg+XW: 131072 rows, one wave each -> 32768 blocks of 256
  fused_pack_xw_kernel<<<dim3(32768), dim3(256), 0, stream>>>(
      graphs, features, conv_w, P, dinv, Y);
  // Aggregation + head: one block of 512 per batch element
  agg_head_kernel<<<dim3(Bn), dim3(512), 0, stream>>>(
      P, dinv, Y, lin_w, lin_b, conv_b, out);
}